// Round 1
// baseline (621.888 us; speedup 1.0000x reference)
//
#include <hip/hip_runtime.h>

#define B_    10000
#define T_    80
#define E_    100
#define U_    64
#define RB_   32      // batch rows per block
#define NTHR  256     // 8 threads per row, 8 units per thread
#define HPAD  68      // padded h stride: (68 % 32)=4 -> rows spread across banks

__global__ __launch_bounds__(NTHR, 2)
void rnn_fused(const int* __restrict__ tokens, const float* __restrict__ emb,
               const float* __restrict__ Wx, const float* __restrict__ Wh,
               const float* __restrict__ bias, const float* __restrict__ Wfc,
               const float* __restrict__ bfc, float* __restrict__ out)
{
    __shared__ __align__(16) float Wxs[E_ * U_];     // 25.6 KB
    __shared__ __align__(16) float Whs[U_ * U_];     // 16 KB
    __shared__ __align__(16) float xs[RB_ * E_];     // 12.8 KB, per-step x tile
    __shared__ __align__(16) float hs[RB_ * HPAD];   // 8.7 KB, hidden state
    __shared__ float bs[U_];
    __shared__ int   toks[RB_ * T_];                 // 10.2 KB

    const int tid  = threadIdx.x;
    const int r    = tid >> 3;      // row within block: 0..31
    const int g    = tid & 7;       // unit-group: 0..7
    const int u0   = g << 3;        // first unit of this thread's 8
    const int row0 = blockIdx.x * RB_;
    const int grow = row0 + r;

    // ---- one-time staging ----
    for (int i = tid; i < E_ * U_; i += NTHR) Wxs[i] = Wx[i];
    for (int i = tid; i < U_ * U_; i += NTHR) Whs[i] = Wh[i];
    if (tid < U_) bs[tid] = bias[tid];
    for (int i = tid; i < RB_ * T_; i += NTHR) {
        int rr = i / T_;
        int tt = i - rr * T_;
        int gr = row0 + rr;
        toks[i] = (gr < B_) ? tokens[gr * T_ + tt] : 0;
    }
    for (int i = tid; i < RB_ * HPAD; i += NTHR) hs[i] = 0.0f;
    __syncthreads();

    float hreg[8];
    #pragma unroll
    for (int j = 0; j < 8; ++j) hreg[j] = 0.0f;

    float* xrow_w       = xs + r * E_;
    const float* xrow   = xs + r * E_;
    const float* hrow   = hs + r * HPAD;

    for (int t = 0; t < T_; ++t) {
        // ---- stage x(t): gather one emb row per batch row (coalesced 32B chunks) ----
        {
            int tok = toks[r * T_ + t];
            const float* erow = emb + tok * E_;
            #pragma unroll
            for (int i = 0; i < 13; ++i) {
                int k = g + (i << 3);
                if (k < E_) xrow_w[k] = erow[k];
            }
        }
        __syncthreads();   // x(t) visible; h(t-1) writes from prev iter visible

        float acc[8];
        #pragma unroll
        for (int j = 0; j < 8; ++j) acc[j] = bs[u0 + j];

        // ---- projection: acc += x[r,:] @ Wx[:, u0..u0+7] ----
        #pragma unroll
        for (int k = 0; k < E_; k += 4) {
            float4 xv = *reinterpret_cast<const float4*>(xrow + k);
            const float* xk = reinterpret_cast<const float*>(&xv);
            #pragma unroll
            for (int kk = 0; kk < 4; ++kk) {
                float4 w0 = *reinterpret_cast<const float4*>(Wxs + (k + kk) * U_ + u0);
                float4 w1 = *reinterpret_cast<const float4*>(Wxs + (k + kk) * U_ + u0 + 4);
                float xx = xk[kk];
                acc[0] += xx * w0.x; acc[1] += xx * w0.y;
                acc[2] += xx * w0.z; acc[3] += xx * w0.w;
                acc[4] += xx * w1.x; acc[5] += xx * w1.y;
                acc[6] += xx * w1.z; acc[7] += xx * w1.w;
            }
        }

        // ---- recurrence: acc += h[r,:] @ Wh[:, u0..u0+7] ----
        #pragma unroll
        for (int k = 0; k < U_; k += 4) {
            float4 hv = *reinterpret_cast<const float4*>(hrow + k);
            const float* hk = reinterpret_cast<const float*>(&hv);
            #pragma unroll
            for (int kk = 0; kk < 4; ++kk) {
                float4 w0 = *reinterpret_cast<const float4*>(Whs + (k + kk) * U_ + u0);
                float4 w1 = *reinterpret_cast<const float4*>(Whs + (k + kk) * U_ + u0 + 4);
                float hh = hk[kk];
                acc[0] += hh * w0.x; acc[1] += hh * w0.y;
                acc[2] += hh * w0.z; acc[3] += hh * w0.w;
                acc[4] += hh * w1.x; acc[5] += hh * w1.y;
                acc[6] += hh * w1.z; acc[7] += hh * w1.w;
            }
        }

        // ---- h = tanh(acc)  (fast: tanh(|x|) = 1 - 2/(e^{2|x|}+1), sign restored) ----
        #pragma unroll
        for (int j = 0; j < 8; ++j) {
            float v  = acc[j];
            float e  = __expf(2.0f * fabsf(v));     // overflow -> inf -> tanh -> 1
            float tn = 1.0f - 2.0f / (e + 1.0f);
            hreg[j] = copysignf(tn, v);
        }

        __syncthreads();   // all reads of h(t-1) and x(t) complete
        #pragma unroll
        for (int j = 0; j < 8; ++j) hs[r * HPAD + u0 + j] = hreg[j];
    }

    // ---- logits + sigmoid ----
    float part = 0.0f;
    #pragma unroll
    for (int j = 0; j < 8; ++j) part += hreg[j] * Wfc[u0 + j];
    part += __shfl_xor(part, 1);
    part += __shfl_xor(part, 2);
    part += __shfl_xor(part, 4);
    if (g == 0 && grow < B_) {
        float logit = part + bfc[0];
        float s;
        if (logit >= 0.0f) s = 1.0f / (1.0f + __expf(-logit));
        else { float e = __expf(logit); s = e / (1.0f + e); }
        out[grow] = s;
    }
}

extern "C" void kernel_launch(void* const* d_in, const int* in_sizes, int n_in,
                              void* d_out, int out_size, void* d_ws, size_t ws_size,
                              hipStream_t stream) {
    const int*   tokens = (const int*)  d_in[0];
    const float* emb    = (const float*)d_in[1];
    const float* Wx     = (const float*)d_in[2];
    const float* Wh     = (const float*)d_in[3];
    const float* b      = (const float*)d_in[4];
    const float* Wfc    = (const float*)d_in[5];
    const float* bfc    = (const float*)d_in[6];
    float* out          = (float*)d_out;

    int grid = (B_ + RB_ - 1) / RB_;   // 313
    rnn_fused<<<grid, NTHR, 0, stream>>>(tokens, emb, Wx, Wh, b, Wfc, bfc, out);
}